// Round 3
// baseline (3076.637 us; speedup 1.0000x reference)
//
#include <hip/hip_runtime.h>
#include <hip/hip_bf16.h>

// ConvGeodesic as one f16x3 split-precision MFMA GEMM with fused angular-max epilogue.
//   k_ksum:   Ksum = sum_k kernel                          (1.3 MB ws)
//   k_wt:     WT[q=(r,o)][k'=(seg,j,i,n)] f16 hi|hi|lo     (15.7 MB ws)
//   k_interp: X[row][(j,i,n)] f16 hi|lo  barycentric pullback (chunked to fit ws)
//   k_gemm_fused: per 128 rows, loop r=0..7: 128x128 MFMA tile (K'=7680),
//                 relu -> row norms -> running argmax -> write winner to out.
// Workspace demand adapts to ws_size via row-chunking (min ~18 MB).

typedef _Float16 f16;
typedef _Float16 f16x8 __attribute__((ext_vector_type(8)));
typedef float f32x4 __attribute__((ext_vector_type(4)));

#define B_   2
#define M_   20000
#define T_   8
#define R_   5
#define NIN  64
#define O_   128
#define K_   4

#define PTS   (B_*M_)      // 40000
#define MPAD  40064        // 313*128
#define KSEG  2560         // T_*R_*NIN
#define KPHY  5120         // physical X cols: [hi | lo]
#define KLOG  7680         // logical GEMM K: hi*Whi + lo*Whi + hi*Wlo
#define NQ    1024         // T_*O_
#define SCALE 16.0f        // keeps f16 "lo" parts in normal range
#define INVSS (1.0f/(SCALE*SCALE))

__global__ void k_ksum(const float* __restrict__ kern, float* __restrict__ ksum) {
    int i = blockIdx.x * 256 + threadIdx.x;
    const int total = T_ * R_ * O_ * NIN;  // 327680
    if (i >= total) return;
    float s = 0.f;
#pragma unroll
    for (int k = 0; k < K_; k++) s += kern[k * total + i];
    ksum[i] = s;
}

__global__ void k_wt(const float* __restrict__ ksum, f16* __restrict__ wt) {
    int idx = blockIdx.x * 256 + threadIdx.x;  // over NQ*KSEG
    const int total = NQ * KSEG;
    if (idx >= total) return;
    int q = idx / KSEG;
    int k = idx - q * KSEG;
    int r = q >> 7, o = q & 127;
    int j = k / 320;
    int rem = k - j * 320;
    int i = rem >> 6, n = rem & 63;
    int t = (j + r) & 7;
    float v = SCALE * ksum[((((t * R_ + i) * O_ + o) << 6) + n)];
    f16 hi = (f16)v;
    f16 lo = (f16)(v - (float)hi);
    f16* row = wt + (size_t)q * KLOG;
    row[k] = hi;            // seg0: pairs x_hi
    row[k + KSEG] = hi;     // seg1: pairs x_lo
    row[k + 2 * KSEG] = lo; // seg2: pairs x_hi
}

__global__ void k_interp(const float* __restrict__ sig, const float* __restrict__ bw,
                         const int* __restrict__ bi, f16* __restrict__ X,
                         int pt0, int rows_pad) {
    int wid = blockIdx.x * 4 + (threadIdx.x >> 6);  // one wave per (local row, j, i)
    int lane = threadIdx.x & 63;                    // lane = n
    if (wid >= rows_pad * (T_ * R_)) return;
    int lr = wid / (T_ * R_);
    int ji = wid - lr * (T_ * R_);
    int pt = pt0 + lr;
    int j = ji / R_, i = ji - j * R_;
    int col = j * 320 + i * 64 + lane;
    f16* row = X + (size_t)lr * KPHY;
    if (pt >= PTS) {  // zero-fill pad rows: poison must not reach MFMA
        row[col] = (f16)0.f;
        row[col + KSEG] = (f16)0.f;
        return;
    }
    int b = (pt >= M_) ? 1 : 0;
    size_t base = (size_t)pt * (T_ * R_ * 3) + (size_t)ji * 3;
    float w0 = bw[base], w1 = bw[base + 1], w2 = bw[base + 2];
    int i0 = bi[base], i1 = bi[base + 1], i2 = bi[base + 2];
    const float* sb = sig + (size_t)b * M_ * NIN;
    float x = w0 * sb[(size_t)i0 * NIN + lane];
    x = fmaf(w1, sb[(size_t)i1 * NIN + lane], x);
    x = fmaf(w2, sb[(size_t)i2 * NIN + lane], x);
    x *= SCALE;
    f16 hi = (f16)x;
    f16 lo = (f16)(x - (float)hi);
    row[col] = hi;
    row[col + KSEG] = lo;
}

__global__ __launch_bounds__(256, 2) void k_gemm_fused(
    const f16* __restrict__ X, const f16* __restrict__ WT,
    float* __restrict__ out, int pt0) {
    __shared__ __align__(16) f16 As[128 * 32];
    __shared__ __align__(16) f16 Bs[128 * 32];
    __shared__ float sred[2][128];
    int m0 = blockIdx.x * 128;          // local (chunk) row base
    int t = threadIdx.x;
    int w = t >> 6, lane = t & 63;
    int wr = w >> 1, wc = w & 1;        // 2x2 waves over 128x128
    int lq = lane >> 4;                 // 0..3
    int lr16 = lane & 15;               // 0..15

    f32x4 best[4][4];
    float bestss[4][4];
#pragma unroll
    for (int a = 0; a < 4; a++)
#pragma unroll
        for (int b = 0; b < 4; b++) { best[a][b] = (f32x4){0.f, 0.f, 0.f, 0.f}; bestss[a][b] = -1.f; }

    const f16* Abase = X + (size_t)(m0 + (t >> 2)) * KPHY + (t & 3) * 8;
    f16* AsDst = As + t * 8;            // lane-linear: matches global_load_lds wave-uniform+lane*16
    f16* BsDst = Bs + t * 8;
    const f16* ApA = As + (wr * 64 + lr16) * 32 + lq * 8;
    const f16* BpB = Bs + (wc * 64 + lr16) * 32 + lq * 8;

    for (int r = 0; r < T_; ++r) {
        const f16* Bbase = WT + (size_t)(r * O_ + (t >> 2)) * KLOG + (t & 3) * 8;
        f32x4 acc[4][4];
#pragma unroll
        for (int a = 0; a < 4; a++)
#pragma unroll
            for (int b = 0; b < 4; b++) acc[a][b] = (f32x4){0.f, 0.f, 0.f, 0.f};

        for (int ks = 0; ks < KLOG / 32; ++ks) {
            int k0 = ks * 32;
            int kA = (k0 < KPHY) ? k0 : (k0 - KPHY);  // seg2 re-reads x_hi
            __builtin_amdgcn_global_load_lds(
                (const __attribute__((address_space(1))) void*)(Abase + kA),
                (__attribute__((address_space(3))) void*)AsDst, 16, 0, 0);
            __builtin_amdgcn_global_load_lds(
                (const __attribute__((address_space(1))) void*)(Abase + kA + (size_t)64 * KPHY),
                (__attribute__((address_space(3))) void*)(AsDst + 64 * 32), 16, 0, 0);
            __builtin_amdgcn_global_load_lds(
                (const __attribute__((address_space(1))) void*)(Bbase + k0),
                (__attribute__((address_space(3))) void*)BsDst, 16, 0, 0);
            __builtin_amdgcn_global_load_lds(
                (const __attribute__((address_space(1))) void*)(Bbase + k0 + (size_t)64 * KLOG),
                (__attribute__((address_space(3))) void*)(BsDst + 64 * 32), 16, 0, 0);
            __syncthreads();

            f16x8 af[4], bf[4];
#pragma unroll
            for (int mf = 0; mf < 4; mf++) af[mf] = *(const f16x8*)(ApA + mf * 16 * 32);
#pragma unroll
            for (int nf = 0; nf < 4; nf++) bf[nf] = *(const f16x8*)(BpB + nf * 16 * 32);
#pragma unroll
            for (int mf = 0; mf < 4; mf++)
#pragma unroll
                for (int nf = 0; nf < 4; nf++)
                    acc[mf][nf] = __builtin_amdgcn_mfma_f32_16x16x32_f16(af[mf], bf[nf], acc[mf][nf], 0, 0, 0);
            __syncthreads();
        }

        // relu in place
#pragma unroll
        for (int mf = 0; mf < 4; mf++)
#pragma unroll
            for (int nf = 0; nf < 4; nf++)
#pragma unroll
                for (int jj = 0; jj < 4; jj++)
                    acc[mf][nf][jj] = fmaxf(acc[mf][nf][jj], 0.f);

        // per-row sum of squares over this wave's 64 cols, then cross-wave via LDS
#pragma unroll
        for (int mf = 0; mf < 4; mf++)
#pragma unroll
            for (int jj = 0; jj < 4; jj++) {
                float s = 0.f;
#pragma unroll
                for (int nf = 0; nf < 4; nf++) { float v = acc[mf][nf][jj]; s = fmaf(v, v, s); }
                s += __shfl_xor(s, 1, 64);
                s += __shfl_xor(s, 2, 64);
                s += __shfl_xor(s, 4, 64);
                s += __shfl_xor(s, 8, 64);
                if (lr16 == 0) sred[wc][wr * 64 + mf * 16 + lq * 4 + jj] = s;
            }
        __syncthreads();
#pragma unroll
        for (int mf = 0; mf < 4; mf++)
#pragma unroll
            for (int jj = 0; jj < 4; jj++) {
                int row = wr * 64 + mf * 16 + lq * 4 + jj;
                float tot = sred[0][row] + sred[1][row];
                bool win = tot > bestss[mf][jj];   // strict >: first max, matches argmax
                bestss[mf][jj] = win ? tot : bestss[mf][jj];
#pragma unroll
                for (int nf = 0; nf < 4; nf++)
                    best[mf][nf][jj] = win ? acc[mf][nf][jj] : best[mf][nf][jj];
            }
        __syncthreads();
    }

#pragma unroll
    for (int mf = 0; mf < 4; mf++)
#pragma unroll
        for (int jj = 0; jj < 4; jj++) {
            int row = m0 + wr * 64 + mf * 16 + lq * 4 + jj;
            int pt = pt0 + row;
            if (pt < PTS) {
                float* op = out + (size_t)pt * O_ + wc * 64 + lr16;
#pragma unroll
                for (int nf = 0; nf < 4; nf++) op[nf * 16] = best[mf][nf][jj] * INVSS;
            }
        }
}

extern "C" void kernel_launch(void* const* d_in, const int* in_sizes, int n_in,
                              void* d_out, int out_size, void* d_ws, size_t ws_size,
                              hipStream_t stream) {
    const float* sig = (const float*)d_in[0];
    const float* bw = (const float*)d_in[1];
    const int* bi = (const int*)d_in[2];
    const float* kern = (const float*)d_in[3];
    float* out = (float*)d_out;
    char* ws = (char*)d_ws;

    const size_t sz_ksum = (size_t)T_ * R_ * O_ * NIN * sizeof(float);  // 1,310,720
    const size_t sz_wt = (size_t)NQ * KLOG * sizeof(f16);               // 15,728,640
    float* ksum = (float*)ws;
    f16* WT = (f16*)(ws + sz_ksum);
    f16* X = (f16*)(ws + sz_ksum + sz_wt);

    size_t persist = sz_ksum + sz_wt;
    size_t avail = (ws_size > persist) ? (ws_size - persist) : 0;
    long maxrows = (long)(avail / ((size_t)KPHY * sizeof(f16)));  // 10240 B per row
    int chunk = (int)((maxrows / 128) * 128);
    if (chunk < 128) chunk = 128;
    if (chunk > MPAD) chunk = MPAD;

    k_ksum<<<(T_ * R_ * O_ * NIN + 255) / 256, 256, 0, stream>>>(kern, ksum);
    k_wt<<<(NQ * KSEG + 255) / 256, 256, 0, stream>>>(ksum, WT);

    for (int pt0 = 0; pt0 < PTS; pt0 += chunk) {
        int rem = PTS - pt0;
        int rows = (rem < chunk) ? rem : chunk;
        int rows_pad = (rows + 127) & ~127;
        int nw = rows_pad * T_ * R_;
        k_interp<<<(nw + 3) / 4, 256, 0, stream>>>(sig, bw, bi, X, pt0, rows_pad);
        k_gemm_fused<<<rows_pad / 128, 256, 0, stream>>>(X, WT, out, pt0);
    }
}

// Round 4
// 2339.436 us; speedup vs baseline: 1.3151x; 1.3151x over previous
//
#include <hip/hip_runtime.h>
#include <hip/hip_bf16.h>

// ConvGeodesic as one f16x3 split-precision MFMA GEMM with fused angular-max epilogue.
//   k_ksum:   Ksum = sum_k kernel
//   k_wt:     WT[q=(r,o)][k'=(seg,j,i,n)] f16 hi|hi|lo
//   k_interp: X[row][(j,i,n)] f16 hi|lo  (grid-strided, 2048 blocks)
//   k_gemm_fused: 64-row blocks (grid 626), BK=64 double-buffered 2-phase
//     pipeline with counted vmcnt(6), XOR-swizzled LDS (conflict-free),
//     flattened (r,ks) loop; per-r: relu -> row norms -> running argmax.

typedef _Float16 f16;
typedef _Float16 f16x8 __attribute__((ext_vector_type(8)));
typedef float f32x4 __attribute__((ext_vector_type(4)));

#define B_   2
#define M_   20000
#define T_   8
#define R_   5
#define NIN  64
#define O_   128
#define K_   4

#define PTS   (B_*M_)      // 40000
#define KSEG  2560         // T_*R_*NIN
#define KPHY  5120         // X cols: [hi | lo]
#define KLOG  7680         // GEMM K: hi*Whi + lo*Whi + hi*Wlo
#define NQ    1024         // T_*O_
#define SCALE 16.0f
#define INVSS (1.0f/(SCALE*SCALE))

#define BM    64
#define BK    64
#define NSTEP (KLOG/BK)    // 120 K-steps per rotation
#define TSTEPS (T_*NSTEP)  // 960

__global__ void k_ksum(const float* __restrict__ kern, float* __restrict__ ksum) {
    int i = blockIdx.x * 256 + threadIdx.x;
    const int total = T_ * R_ * O_ * NIN;
    if (i >= total) return;
    float s = 0.f;
#pragma unroll
    for (int k = 0; k < K_; k++) s += kern[k * total + i];
    ksum[i] = s;
}

__global__ void k_wt(const float* __restrict__ ksum, f16* __restrict__ wt) {
    int idx = blockIdx.x * 256 + threadIdx.x;  // over NQ*KSEG
    const int total = NQ * KSEG;
    if (idx >= total) return;
    int q = idx / KSEG;
    int k = idx - q * KSEG;
    int r = q >> 7, o = q & 127;
    int j = k / 320;
    int rem = k - j * 320;
    int i = rem >> 6, n = rem & 63;
    int t = (j + r) & 7;
    float v = SCALE * ksum[((((t * R_ + i) * O_ + o) << 6) + n)];
    f16 hi = (f16)v;
    f16 lo = (f16)(v - (float)hi);
    f16* row = wt + (size_t)q * KLOG;
    row[k] = hi;
    row[k + KSEG] = hi;
    row[k + 2 * KSEG] = lo;
}

// grid-strided: one wave per (local row, j); 5 i-iterations inside.
__global__ void k_interp(const float* __restrict__ sig, const float* __restrict__ bw,
                         const int* __restrict__ bi, f16* __restrict__ X,
                         int pt0, int rows_pad) {
    int nwaves = gridDim.x * 4;
    int wav = (blockIdx.x * 256 + threadIdx.x) >> 6;
    int lane = threadIdx.x & 63;  // lane = n
    int ntask = rows_pad * T_;
    for (int task = wav; task < ntask; task += nwaves) {
        int lr = task >> 3;       // T_ == 8
        int j = task & 7;
        int pt = pt0 + lr;
        f16* rowp = X + (size_t)lr * KPHY + j * 320;
        if (pt >= PTS) {
#pragma unroll
            for (int i = 0; i < R_; i++) {
                rowp[i * 64 + lane] = (f16)0.f;
                rowp[KSEG + i * 64 + lane] = (f16)0.f;
            }
            continue;
        }
        int b = (pt >= M_) ? 1 : 0;
        const float* sb = sig + (size_t)b * M_ * NIN;
        size_t base = (size_t)pt * 120 + j * 15;
#pragma unroll
        for (int i = 0; i < R_; i++) {
            float w0 = bw[base + i * 3], w1 = bw[base + i * 3 + 1], w2 = bw[base + i * 3 + 2];
            int i0 = bi[base + i * 3], i1 = bi[base + i * 3 + 1], i2 = bi[base + i * 3 + 2];
            float x = w0 * sb[(size_t)i0 * NIN + lane];
            x = fmaf(w1, sb[(size_t)i1 * NIN + lane], x);
            x = fmaf(w2, sb[(size_t)i2 * NIN + lane], x);
            x *= SCALE;
            f16 hi = (f16)x;
            f16 lo = (f16)(x - (float)hi);
            rowp[i * 64 + lane] = hi;
            rowp[KSEG + i * 64 + lane] = lo;
        }
    }
}

__global__ __launch_bounds__(256, 2) void k_gemm_fused(
    const f16* __restrict__ X, const f16* __restrict__ WT,
    float* __restrict__ out, int pt0) {
    // dbuf LDS, 48 KiB: As [2][64][64], Bs [2][128][64] (halfs)
    __shared__ __align__(16) f16 As[2][64 * 64];
    __shared__ __align__(16) f16 Bs[2][128 * 64];
    __shared__ float sred[2][BM];
    int m0 = blockIdx.x * BM;
    int t = threadIdx.x;
    int w = t >> 6, lane = t & 63;
    int wr = w >> 1, wc = w & 1;   // 2x2 waves over 64x128
    int lq = lane >> 4;            // 0..3 (k-chunk)
    int lr16 = lane & 15;          // row-in-frag / col-in-C

    // staging thread map: row = t>>3 (+32*call), slot' = t&7 of 8x16B slots.
    // read-side XOR swizzle chunk^= (row&7); source pre-swizzled to match.
    int arow = t >> 3;
    int aswz = ((t & 7) ^ (arow & 7)) << 3;  // halfs
    int swzb = lr16 & 7;                     // read-side row&7 (16/32/64 = 0 mod 8)

    f32x4 acc[2][4], best[2][4];
    float bestss[2][4];
#pragma unroll
    for (int a = 0; a < 2; a++)
#pragma unroll
        for (int b = 0; b < 4; b++) {
            acc[a][b] = (f32x4){0.f, 0.f, 0.f, 0.f};
            best[a][b] = (f32x4){0.f, 0.f, 0.f, 0.f};
            bestss[a][b] = -1.f;
        }

    const f16* Xrow0 = X + (size_t)(m0 + arow) * KPHY + aswz;
    const f16* Xrow1 = X + (size_t)(m0 + arow + 32) * KPHY + aswz;

#define STAGE(S, BUF) do {                                                            \
        int rr_ = (S) / NSTEP;                                                        \
        int k0_ = ((S) - rr_ * NSTEP) * BK;                                           \
        int kA_ = (k0_ < KPHY) ? k0_ : k0_ - KPHY;                                    \
        const f16* bb_ = WT + (size_t)(rr_ * O_ + arow) * KLOG + k0_ + aswz;          \
        __builtin_amdgcn_global_load_lds(                                             \
            (const __attribute__((address_space(1))) void*)(Xrow0 + kA_),             \
            (__attribute__((address_space(3))) void*)(&As[BUF][t * 8]), 16, 0, 0);    \
        __builtin_amdgcn_global_load_lds(                                             \
            (const __attribute__((address_space(1))) void*)(Xrow1 + kA_),             \
            (__attribute__((address_space(3))) void*)(&As[BUF][2048 + t * 8]), 16, 0, 0); \
        __builtin_amdgcn_global_load_lds(                                             \
            (const __attribute__((address_space(1))) void*)(bb_),                     \
            (__attribute__((address_space(3))) void*)(&Bs[BUF][t * 8]), 16, 0, 0);    \
        __builtin_amdgcn_global_load_lds(                                             \
            (const __attribute__((address_space(1))) void*)(bb_ + (size_t)32 * KLOG), \
            (__attribute__((address_space(3))) void*)(&Bs[BUF][2048 + t * 8]), 16, 0, 0); \
        __builtin_amdgcn_global_load_lds(                                             \
            (const __attribute__((address_space(1))) void*)(bb_ + (size_t)64 * KLOG), \
            (__attribute__((address_space(3))) void*)(&Bs[BUF][4096 + t * 8]), 16, 0, 0); \
        __builtin_amdgcn_global_load_lds(                                             \
            (const __attribute__((address_space(1))) void*)(bb_ + (size_t)96 * KLOG), \
            (__attribute__((address_space(3))) void*)(&Bs[BUF][6144 + t * 8]), 16, 0, 0); \
    } while (0)

    STAGE(0, 0);

    for (int s = 0; s < TSTEPS; ++s) {
        int cur = s & 1;
        if (s + 1 < TSTEPS) {
            STAGE(s + 1, cur ^ 1);
            asm volatile("s_waitcnt vmcnt(6)" ::: "memory");  // cur's 6 staged, next's 6 in flight
        } else {
            asm volatile("s_waitcnt vmcnt(0)" ::: "memory");
        }
        __builtin_amdgcn_s_barrier();
        __builtin_amdgcn_sched_barrier(0);

        const f16* Ac = &As[cur][0];
        const f16* Bc = &Bs[cur][0];
#pragma unroll
        for (int kk = 0; kk < 2; ++kk) {
            int ch = ((kk * 4 + lq) ^ swzb) * 8;
            f16x8 af[2], bf[4];
#pragma unroll
            for (int mf = 0; mf < 2; mf++)
                af[mf] = *(const f16x8*)(Ac + (wr * 32 + mf * 16 + lr16) * 64 + ch);
#pragma unroll
            for (int nf = 0; nf < 4; nf++)
                bf[nf] = *(const f16x8*)(Bc + (wc * 64 + nf * 16 + lr16) * 64 + ch);
#pragma unroll
            for (int mf = 0; mf < 2; mf++)
#pragma unroll
                for (int nf = 0; nf < 4; nf++)
                    acc[mf][nf] = __builtin_amdgcn_mfma_f32_16x16x32_f16(af[mf], bf[nf], acc[mf][nf], 0, 0, 0);
        }
        __builtin_amdgcn_sched_barrier(0);
        __builtin_amdgcn_s_barrier();

        if (((s + 1) % NSTEP) == 0) {
            // end of rotation r: relu, row norms, running argmax
#pragma unroll
            for (int mf = 0; mf < 2; mf++)
#pragma unroll
                for (int nf = 0; nf < 4; nf++)
#pragma unroll
                    for (int jj = 0; jj < 4; jj++)
                        acc[mf][nf][jj] = fmaxf(acc[mf][nf][jj], 0.f);
#pragma unroll
            for (int mf = 0; mf < 2; mf++)
#pragma unroll
                for (int jj = 0; jj < 4; jj++) {
                    float ss = 0.f;
#pragma unroll
                    for (int nf = 0; nf < 4; nf++) { float v = acc[mf][nf][jj]; ss = fmaf(v, v, ss); }
                    ss += __shfl_xor(ss, 1, 64);
                    ss += __shfl_xor(ss, 2, 64);
                    ss += __shfl_xor(ss, 4, 64);
                    ss += __shfl_xor(ss, 8, 64);
                    if (lr16 == 0) sred[wc][wr * 32 + mf * 16 + lq * 4 + jj] = ss;
                }
            __syncthreads();
#pragma unroll
            for (int mf = 0; mf < 2; mf++)
#pragma unroll
                for (int jj = 0; jj < 4; jj++) {
                    int row = wr * 32 + mf * 16 + lq * 4 + jj;
                    float tot = sred[0][row] + sred[1][row];
                    bool win = tot > bestss[mf][jj];  // strict >: first max = argmax
                    bestss[mf][jj] = win ? tot : bestss[mf][jj];
#pragma unroll
                    for (int nf = 0; nf < 4; nf++) {
                        best[mf][nf][jj] = win ? acc[mf][nf][jj] : best[mf][nf][jj];
                        acc[mf][nf][jj] = 0.f;
                    }
                }
            __syncthreads();
        }
    }

#pragma unroll
    for (int mf = 0; mf < 2; mf++)
#pragma unroll
        for (int jj = 0; jj < 4; jj++) {
            int row = m0 + wr * 32 + mf * 16 + lq * 4 + jj;
            int pt = pt0 + row;
            if (pt < PTS) {
                float* op = out + (size_t)pt * O_ + wc * 64 + lr16;
#pragma unroll
                for (int nf = 0; nf < 4; nf++) op[nf * 16] = best[mf][nf][jj] * INVSS;
            }
        }
#undef STAGE
}

extern "C" void kernel_launch(void* const* d_in, const int* in_sizes, int n_in,
                              void* d_out, int out_size, void* d_ws, size_t ws_size,
                              hipStream_t stream) {
    const float* sig = (const float*)d_in[0];
    const float* bw = (const float*)d_in[1];
    const int* bi = (const int*)d_in[2];
    const float* kern = (const float*)d_in[3];
    float* out = (float*)d_out;
    char* ws = (char*)d_ws;

    const size_t sz_ksum = (size_t)T_ * R_ * O_ * NIN * sizeof(float);
    const size_t sz_wt = (size_t)NQ * KLOG * sizeof(f16);
    float* ksum = (float*)ws;
    f16* WT = (f16*)(ws + sz_ksum);
    f16* X = (f16*)(ws + sz_ksum + sz_wt);

    size_t persist = sz_ksum + sz_wt;
    size_t avail = (ws_size > persist) ? (ws_size - persist) : 0;
    long maxrows = (long)(avail / ((size_t)KPHY * sizeof(f16)));
    int chunk = (int)((maxrows / BM) * BM);
    if (chunk < BM) chunk = BM;
    const int PTS_PAD = ((PTS + BM - 1) / BM) * BM;
    if (chunk > PTS_PAD) chunk = PTS_PAD;

    k_ksum<<<(T_ * R_ * O_ * NIN + 255) / 256, 256, 0, stream>>>(kern, ksum);
    k_wt<<<(NQ * KSEG + 255) / 256, 256, 0, stream>>>(ksum, WT);

    for (int pt0 = 0; pt0 < PTS; pt0 += chunk) {
        int rem = PTS - pt0;
        int rows = (rem < chunk) ? rem : chunk;
        int rows_pad = (rows + BM - 1) & ~(BM - 1);
        k_interp<<<2048, 256, 0, stream>>>(sig, bw, bi, X, pt0, rows_pad);
        k_gemm_fused<<<rows_pad / BM, 256, 0, stream>>>(X, WT, out, pt0);
    }
}

// Round 5
// 1649.842 us; speedup vs baseline: 1.8648x; 1.4180x over previous
//
#include <hip/hip_runtime.h>
#include <hip/hip_bf16.h>

// ConvGeodesic as one f16x3 split-precision MFMA GEMM, all 8 rotations per
// K-sweep (X read ONCE), fused relu/norm/argmax epilogue from live registers.
//   k_ksum:   Ksum = sum_k kernel
//   k_wt:     WT[q=(r,o)][k'=(seg,j,i,n)] f16 hi|hi|lo
//   k_interp: X[row][(j,i,n)] f16 hi|lo  (grid-strided; shfl-broadcast weights)
//   k_gemm_fused: BM=64 x BN=1024, BK=32, 512 thr / 8 waves, dbuf LDS 138 KB,
//     counted vmcnt(9) 2-phase pipeline, XOR-swizzled LDS; epilogue once.

typedef _Float16 f16;
typedef _Float16 f16x8 __attribute__((ext_vector_type(8)));
typedef float f32x4 __attribute__((ext_vector_type(4)));

#define B_   2
#define M_   20000
#define T_   8
#define R_   5
#define NIN  64
#define O_   128
#define K_   4

#define PTS   (B_*M_)      // 40000
#define KSEG  2560         // T_*R_*NIN
#define KPHY  5120         // X cols: [hi | lo]
#define KLOG  7680         // GEMM K: hi*Whi + lo*Whi + hi*Wlo
#define NQ    1024         // T_*O_
#define SCALE 16.0f
#define INVSS (1.0f/(SCALE*SCALE))

#define BM    64
#define BK    32
#define TS    (KLOG/BK)    // 240 K-steps, single sweep covers all rotations

__global__ void k_ksum(const float* __restrict__ kern, float* __restrict__ ksum) {
    int i = blockIdx.x * 256 + threadIdx.x;
    const int total = T_ * R_ * O_ * NIN;
    if (i >= total) return;
    float s = 0.f;
#pragma unroll
    for (int k = 0; k < K_; k++) s += kern[k * total + i];
    ksum[i] = s;
}

__global__ void k_wt(const float* __restrict__ ksum, f16* __restrict__ wt) {
    int idx = blockIdx.x * 256 + threadIdx.x;  // over NQ*KSEG
    const int total = NQ * KSEG;
    if (idx >= total) return;
    int q = idx / KSEG;
    int k = idx - q * KSEG;
    int r = q >> 7, o = q & 127;
    int j = k / 320;
    int rem = k - j * 320;
    int i = rem >> 6, n = rem & 63;
    int t = (j + r) & 7;
    float v = SCALE * ksum[((((t * R_ + i) * O_ + o) << 6) + n)];
    f16 hi = (f16)v;
    f16 lo = (f16)(v - (float)hi);
    f16* row = wt + (size_t)q * KLOG;
    row[k] = hi;
    row[k + KSEG] = hi;
    row[k + 2 * KSEG] = lo;
}

// grid-strided: one wave per (local row, j); lanes 0-14 load bw/bi, shfl-broadcast.
__global__ void k_interp(const float* __restrict__ sig, const float* __restrict__ bw,
                         const int* __restrict__ bi, f16* __restrict__ X,
                         int pt0, int rows_pad) {
    int nwaves = gridDim.x * 4;
    int wav = (blockIdx.x * 256 + threadIdx.x) >> 6;
    int lane = threadIdx.x & 63;  // lane = n
    int ntask = rows_pad * T_;
    for (int task = wav; task < ntask; task += nwaves) {
        int lr = task >> 3;       // T_ == 8
        int j = task & 7;
        int pt = pt0 + lr;
        f16* rowp = X + (size_t)lr * KPHY + j * 320;
        if (pt >= PTS) {
#pragma unroll
            for (int i = 0; i < R_; i++) {
                rowp[i * 64 + lane] = (f16)0.f;
                rowp[KSEG + i * 64 + lane] = (f16)0.f;
            }
            continue;
        }
        int b = (pt >= M_) ? 1 : 0;
        const float* sb = sig + (size_t)b * M_ * NIN;
        size_t base = (size_t)pt * 120 + j * 15;
        float wv = 0.f;
        int iv = 0;
        if (lane < 15) { wv = bw[base + lane]; iv = bi[base + lane]; }
#pragma unroll
        for (int i = 0; i < R_; i++) {
            float w0 = __shfl(wv, i * 3 + 0, 64);
            float w1 = __shfl(wv, i * 3 + 1, 64);
            float w2 = __shfl(wv, i * 3 + 2, 64);
            int i0 = __shfl(iv, i * 3 + 0, 64);
            int i1 = __shfl(iv, i * 3 + 1, 64);
            int i2 = __shfl(iv, i * 3 + 2, 64);
            float x = w0 * sb[(size_t)i0 * NIN + lane];
            x = fmaf(w1, sb[(size_t)i1 * NIN + lane], x);
            x = fmaf(w2, sb[(size_t)i2 * NIN + lane], x);
            x *= SCALE;
            f16 hi = (f16)x;
            f16 lo = (f16)(x - (float)hi);
            rowp[i * 64 + lane] = hi;
            rowp[KSEG + i * 64 + lane] = lo;
        }
    }
}

__global__ __launch_bounds__(512, 2) void k_gemm_fused(
    const f16* __restrict__ X, const f16* __restrict__ WT,
    float* __restrict__ out, int pt0) {
    // dbuf LDS: As [2][64][32], Bs [2][1024][32] halfs; sred 2 KB. 138 KB total.
    __shared__ __align__(16) f16 As[2][64 * 32];
    __shared__ __align__(16) f16 Bs[2][1024 * 32];
    __shared__ float sred[8][64];
    const int m0 = blockIdx.x * BM;
    const int t = threadIdx.x;
    const int w = t >> 6, lane = t & 63;
    const int wr = w >> 2, wc = w & 3;      // 2m x 4n wave grid; wave tile 32x256
    const int lq = lane >> 4, lr16 = lane & 15;
    const int flane = (lr16 >> 1) & 3;      // read-side swizzle f(row) = (row>>1)&3
    const int src_off = (((lane & 3) ^ ((lane >> 3) & 3)) << 3);  // staging pre-swizzle

    f32x4 acc[2][16];
#pragma unroll
    for (int a = 0; a < 2; a++)
#pragma unroll
        for (int b = 0; b < 16; b++) acc[a][b] = (f32x4){0.f, 0.f, 0.f, 0.f};

    // A: wave w stages rows 8w..8w+7 (lanes 0-31); B: wave w rows w*128..w*128+127 (8 calls)
    const f16* pA = X + (size_t)(m0 + 8 * w + ((lane & 31) >> 2)) * KPHY + src_off;
    const f16* pB = WT + (size_t)(w * 128 + (lane >> 2)) * KLOG + src_off;

#define STAGE(S, BUF) do {                                                                \
        int k0_ = (S) * BK;                                                               \
        int kA_ = k0_ - ((k0_ >= KPHY) ? KPHY : 0); /* seg2 re-reads x_hi */              \
        if (lane < 32)                                                                    \
            __builtin_amdgcn_global_load_lds(                                             \
                (const __attribute__((address_space(1))) void*)(pA + kA_),                \
                (__attribute__((address_space(3))) void*)(&As[BUF][w * 256 + (lane & 31) * 8]), \
                16, 0, 0);                                                                \
        _Pragma("unroll")                                                                 \
        for (int i_ = 0; i_ < 8; i_++)                                                    \
            __builtin_amdgcn_global_load_lds(                                             \
                (const __attribute__((address_space(1))) void*)(pB + i_ * 16 * KLOG + k0_), \
                (__attribute__((address_space(3))) void*)(&Bs[BUF][(w * 8 + i_) * 512 + lane * 8]), \
                16, 0, 0);                                                                \
    } while (0)

    STAGE(0, 0);

    for (int s = 0; s < TS; ++s) {
        int cur = s & 1;
        if (s + 1 < TS) {
            STAGE(s + 1, cur ^ 1);
            asm volatile("s_waitcnt vmcnt(9)" ::: "memory");  // this step's 9 landed, next's in flight
        } else {
            asm volatile("s_waitcnt vmcnt(0)" ::: "memory");
        }
        __builtin_amdgcn_s_barrier();
        __builtin_amdgcn_sched_barrier(0);

        const f16* Ac = &As[cur][0];
        const f16* Bc = &Bs[cur][0];
        const int cho = (lq ^ flane) << 3;
        f16x8 af0 = *(const f16x8*)(Ac + (wr * 32 + lr16) * 32 + cho);
        f16x8 af1 = *(const f16x8*)(Ac + (wr * 32 + 16 + lr16) * 32 + cho);
#pragma unroll
        for (int nf = 0; nf < 16; nf++) {
            f16x8 bf = *(const f16x8*)(Bc + (wc * 256 + nf * 16 + lr16) * 32 + cho);
            acc[0][nf] = __builtin_amdgcn_mfma_f32_16x16x32_f16(af0, bf, acc[0][nf], 0, 0, 0);
            acc[1][nf] = __builtin_amdgcn_mfma_f32_16x16x32_f16(af1, bf, acc[1][nf], 0, 0, 0);
        }
        __builtin_amdgcn_sched_barrier(0);
        __builtin_amdgcn_s_barrier();
    }
#undef STAGE

    // epilogue: relu -> per-(row, r) norms -> argmax over r -> winner writes
#pragma unroll
    for (int mf = 0; mf < 2; mf++)
#pragma unroll
        for (int nf = 0; nf < 16; nf++)
#pragma unroll
            for (int jj = 0; jj < 4; jj++)
                acc[mf][nf][jj] = fmaxf(acc[mf][nf][jj], 0.f);

#pragma unroll
    for (int mf = 0; mf < 2; mf++)
#pragma unroll
        for (int jj = 0; jj < 4; jj++)
#pragma unroll
            for (int half = 0; half < 2; half++) {  // wave owns r = 2*wc + half
                float s = 0.f;
#pragma unroll
                for (int nf2 = 0; nf2 < 8; nf2++) {
                    float v = acc[mf][half * 8 + nf2][jj];
                    s = fmaf(v, v, s);
                }
                s += __shfl_xor(s, 1, 64);
                s += __shfl_xor(s, 2, 64);
                s += __shfl_xor(s, 4, 64);
                s += __shfl_xor(s, 8, 64);
                if (lr16 == 0) sred[wc * 2 + half][wr * 32 + mf * 16 + lq * 4 + jj] = s;
            }
    __syncthreads();

#pragma unroll
    for (int mf = 0; mf < 2; mf++)
#pragma unroll
        for (int jj = 0; jj < 4; jj++) {
            int row = wr * 32 + mf * 16 + lq * 4 + jj;
            float bs = sred[0][row];
            int br = 0;
#pragma unroll
            for (int r = 1; r < 8; r++) {
                float v = sred[r][row];
                if (v > bs) { bs = v; br = r; }  // strict >: first max = argmax
            }
            int pt = pt0 + m0 + row;
            if ((br >> 1) == wc && pt < PTS) {
                float* op = out + (size_t)pt * O_ + lr16;
                if (br & 1) {  // static acc indices in both branches (no scratch)
#pragma unroll
                    for (int nf2 = 0; nf2 < 8; nf2++) op[nf2 * 16] = acc[mf][8 + nf2][jj] * INVSS;
                } else {
#pragma unroll
                    for (int nf2 = 0; nf2 < 8; nf2++) op[nf2 * 16] = acc[mf][nf2][jj] * INVSS;
                }
            }
        }
}

extern "C" void kernel_launch(void* const* d_in, const int* in_sizes, int n_in,
                              void* d_out, int out_size, void* d_ws, size_t ws_size,
                              hipStream_t stream) {
    const float* sig = (const float*)d_in[0];
    const float* bw = (const float*)d_in[1];
    const int* bi = (const int*)d_in[2];
    const float* kern = (const float*)d_in[3];
    float* out = (float*)d_out;
    char* ws = (char*)d_ws;

    const size_t sz_ksum = (size_t)T_ * R_ * O_ * NIN * sizeof(float);
    const size_t sz_wt = (size_t)NQ * KLOG * sizeof(f16);
    float* ksum = (float*)ws;
    f16* WT = (f16*)(ws + sz_ksum);
    f16* X = (f16*)(ws + sz_ksum + sz_wt);

    size_t persist = sz_ksum + sz_wt;
    size_t avail = (ws_size > persist) ? (ws_size - persist) : 0;
    long maxrows = (long)(avail / ((size_t)KPHY * sizeof(f16)));
    int chunk = (int)((maxrows / BM) * BM);
    if (chunk < BM) chunk = BM;
    const int PTS_PAD = ((PTS + BM - 1) / BM) * BM;
    if (chunk > PTS_PAD) chunk = PTS_PAD;

    k_ksum<<<(T_ * R_ * O_ * NIN + 255) / 256, 256, 0, stream>>>(kern, ksum);
    k_wt<<<(NQ * KSEG + 255) / 256, 256, 0, stream>>>(ksum, WT);

    for (int pt0 = 0; pt0 < PTS; pt0 += chunk) {
        int rem = PTS - pt0;
        int rows = (rem < chunk) ? rem : chunk;
        int rows_pad = (rows + BM - 1) & ~(BM - 1);
        k_interp<<<2048, 256, 0, stream>>>(sig, bw, bi, X, pt0, rows_pad);
        k_gemm_fused<<<rows_pad / BM, 512, 0, stream>>>(X, WT, out, pt0);
    }
}

// Round 7
// 1456.506 us; speedup vs baseline: 2.1123x; 1.1327x over previous
//
#include <hip/hip_runtime.h>
#include <hip/hip_bf16.h>

// ConvGeodesic: f16x3 split-precision MFMA GEMM (256x256xBK64, m201 geometry)
// writing post-relu conv + per-rotation norms, then an argmax-select pass.
//   k_ksum:   Ksum = sum_k kernel
//   k_wt:     WT[q=(r,o)][k'=(seg,j,i,n)] f16 hi|hi|lo
//   k_interp: X[row][(j,i,n)] f16 hi|lo (scalar-uniform weight loads)
//   k_gemm:   256x256 tile, BK=64, 8 waves (2x4), 2-phase counted vmcnt(8),
//             3-bit XOR LDS swizzle, bijective XCD-chunked block swizzle;
//             epilogue: relu -> conv store + complete norms for 2 rotations.
//   k_select: per point argmax over 8 norms -> copy winning 128 cols.

typedef _Float16 f16;
typedef _Float16 f16x8 __attribute__((ext_vector_type(8)));
typedef float f32x4 __attribute__((ext_vector_type(4)));

#define B_   2
#define M_   20000
#define T_   8
#define R_   5
#define NIN  64
#define O_   128
#define K_   4

#define PTS   (B_*M_)      // 40000
#define PTSPAD 40192       // 157*256
#define KSEG  2560         // T_*R_*NIN
#define KPHY  5120         // X cols: [hi | lo]
#define KLOG  7680         // GEMM K: hi*Whi + lo*Whi + hi*Wlo
#define NQ    1024         // T_*O_
#define SCALE 16.0f
#define INVSS (1.0f/(SCALE*SCALE))

#define BM    256
#define BK    64
#define TS    (KLOG/BK)    // 120 K-steps

__global__ void k_ksum(const float* __restrict__ kern, float* __restrict__ ksum) {
    int i = blockIdx.x * 256 + threadIdx.x;
    const int total = T_ * R_ * O_ * NIN;
    if (i >= total) return;
    float s = 0.f;
#pragma unroll
    for (int k = 0; k < K_; k++) s += kern[k * total + i];
    ksum[i] = s;
}

__global__ void k_wt(const float* __restrict__ ksum, f16* __restrict__ wt) {
    int idx = blockIdx.x * 256 + threadIdx.x;  // over NQ*KSEG
    const int total = NQ * KSEG;
    if (idx >= total) return;
    int q = idx / KSEG;
    int k = idx - q * KSEG;
    int r = q >> 7, o = q & 127;
    int j = k / 320;
    int rem = k - j * 320;
    int i = rem >> 6, n = rem & 63;
    int t = (j + r) & 7;
    float v = SCALE * ksum[((((t * R_ + i) * O_ + o) << 6) + n)];
    f16 hi = (f16)v;
    f16 lo = (f16)(v - (float)hi);
    f16* row = wt + (size_t)q * KLOG;
    row[k] = hi;
    row[k + KSEG] = hi;
    row[k + 2 * KSEG] = lo;
}

// one wave per (local row, j); wave-uniform scalar weight loads.
__global__ void k_interp(const float* __restrict__ sig, const float* __restrict__ bw,
                         const int* __restrict__ bi, f16* __restrict__ X,
                         int pt0, int rows_pad) {
    int nwaves = gridDim.x * 4;
    int wav = (blockIdx.x * 256 + threadIdx.x) >> 6;
    int lane = threadIdx.x & 63;  // lane = n
    int ntask = rows_pad * T_;
    for (int task = wav; task < ntask; task += nwaves) {
        int tu = __builtin_amdgcn_readfirstlane(task);
        int lr = tu >> 3;         // T_ == 8
        int j = tu & 7;
        int pt = pt0 + lr;
        f16* rowp = X + (size_t)lr * KPHY + j * 320;
        if (pt >= PTS) {
#pragma unroll
            for (int i = 0; i < R_; i++) {
                rowp[i * 64 + lane] = (f16)0.f;
                rowp[KSEG + i * 64 + lane] = (f16)0.f;
            }
            continue;
        }
        int b = (pt >= M_) ? 1 : 0;
        const float* sb = sig + (size_t)b * M_ * NIN;
        const float* wp = bw + (size_t)pt * 120 + j * 15;
        const int* ip = bi + (size_t)pt * 120 + j * 15;
#pragma unroll
        for (int i = 0; i < R_; i++) {
            float w0 = wp[i * 3], w1 = wp[i * 3 + 1], w2 = wp[i * 3 + 2];
            int i0 = ip[i * 3], i1 = ip[i * 3 + 1], i2 = ip[i * 3 + 2];
            float x = w0 * sb[(size_t)i0 * NIN + lane];
            x = fmaf(w1, sb[(size_t)i1 * NIN + lane], x);
            x = fmaf(w2, sb[(size_t)i2 * NIN + lane], x);
            x *= SCALE;
            f16 hi = (f16)x;
            f16 lo = (f16)(x - (float)hi);
            rowp[i * 64 + lane] = hi;
            rowp[KSEG + i * 64 + lane] = lo;
        }
    }
}

__global__ __launch_bounds__(512, 1) void k_gemm(
    const f16* __restrict__ X, const f16* __restrict__ WT,
    float* __restrict__ conv, float* __restrict__ norms, int pt0) {
    // dbuf LDS: As/Bs [2][256][64] halfs = 64 KB each; sred 4 KB. 132 KB.
    __shared__ __align__(16) f16 As[2][256 * 64];
    __shared__ __align__(16) f16 Bs[2][256 * 64];
    __shared__ float sred[4][256];

    // bijective XCD-chunked swizzle (m204): consecutive logical ids -> same XCD
    int nwg = gridDim.x;
    int bq = nwg >> 3, br_ = nwg & 7;
    int xcd = blockIdx.x & 7, slot = blockIdx.x >> 3;
    int logical = (xcd < br_ ? xcd * (bq + 1) : br_ * (bq + 1) + (xcd - br_) * bq) + slot;
    int mblk = logical >> 2, nb = logical & 3;  // 4 col-blocks of one row-panel adjacent
    const int m0 = mblk * BM;
    const int n0 = nb * 256;

    const int t = threadIdx.x;
    const int w = t >> 6, lane = t & 63;
    const int wr = w >> 2, wc = w & 3;     // 2m x 4n waves; wave tile 128x64
    const int lq = lane >> 4, lr16 = lane & 15;
    const int fr = lr16 & 7;               // read-side swizzle bits
    const int src_off = (((t & 7) ^ ((t >> 3) & 7)) << 3);  // staging pre-swizzle (halfs)

    f32x4 acc[8][4];
#pragma unroll
    for (int a = 0; a < 8; a++)
#pragma unroll
        for (int b = 0; b < 4; b++) acc[a][b] = (f32x4){0.f, 0.f, 0.f, 0.f};

    const f16* pA = X + (size_t)(m0 + (t >> 3)) * KPHY + src_off;
    const f16* pB = WT + (size_t)(n0 + (t >> 3)) * KLOG + src_off;

#define STAGE(S, BUF) do {                                                            \
        int k0_ = (S) * BK;                                                           \
        int kA_ = k0_ - ((k0_ >= KPHY) ? KPHY : 0); /* seg2 re-reads x_hi */          \
        _Pragma("unroll")                                                             \
        for (int i_ = 0; i_ < 4; i_++)                                                \
            __builtin_amdgcn_global_load_lds(                                         \
                (const __attribute__((address_space(1))) void*)(pA + kA_ + (size_t)i_ * 64 * KPHY), \
                (__attribute__((address_space(3))) void*)(&As[BUF][t * 8 + i_ * 4096]), 16, 0, 0); \
        _Pragma("unroll")                                                             \
        for (int i_ = 0; i_ < 4; i_++)                                                \
            __builtin_amdgcn_global_load_lds(                                         \
                (const __attribute__((address_space(1))) void*)(pB + k0_ + (size_t)i_ * 64 * KLOG), \
                (__attribute__((address_space(3))) void*)(&Bs[BUF][t * 8 + i_ * 4096]), 16, 0, 0); \
    } while (0)

    STAGE(0, 0);

    for (int s = 0; s < TS; ++s) {
        int cur = s & 1;
        if (s + 1 < TS) {
            STAGE(s + 1, cur ^ 1);
            asm volatile("s_waitcnt vmcnt(8)" ::: "memory");  // this step's 8 landed
        } else {
            asm volatile("s_waitcnt vmcnt(0)" ::: "memory");
        }
        __builtin_amdgcn_s_barrier();
        __builtin_amdgcn_sched_barrier(0);

        const f16* Ac = &As[cur][0];
        const f16* Bc = &Bs[cur][0];
#pragma unroll
        for (int kk = 0; kk < 2; ++kk) {
            const int cho = ((kk * 4 + lq) ^ fr) << 3;
            f16x8 af[8], bf[4];
#pragma unroll
            for (int mf = 0; mf < 8; mf++)
                af[mf] = *(const f16x8*)(Ac + (wr * 128 + mf * 16 + lr16) * 64 + cho);
#pragma unroll
            for (int nf = 0; nf < 4; nf++)
                bf[nf] = *(const f16x8*)(Bc + (wc * 64 + nf * 16 + lr16) * 64 + cho);
#pragma unroll
            for (int mf = 0; mf < 8; mf++)
#pragma unroll
                for (int nf = 0; nf < 4; nf++)
                    acc[mf][nf] = __builtin_amdgcn_mfma_f32_16x16x32_f16(af[mf], bf[nf], acc[mf][nf], 0, 0, 0);
        }
        __builtin_amdgcn_sched_barrier(0);
        __builtin_amdgcn_s_barrier();
    }
#undef STAGE

    // epilogue: relu -> conv store (post-relu) + per-row norms for 2 rotations
#pragma unroll
    for (int mf = 0; mf < 8; mf++)
#pragma unroll
        for (int nf = 0; nf < 4; nf++)
#pragma unroll
            for (int jj = 0; jj < 4; jj++)
                acc[mf][nf][jj] = fmaxf(acc[mf][nf][jj], 0.f);

#pragma unroll
    for (int mf = 0; mf < 8; mf++)
#pragma unroll
        for (int jj = 0; jj < 4; jj++) {
            int rowl = wr * 128 + mf * 16 + lq * 4 + jj;
            float s = 0.f;
#pragma unroll
            for (int nf = 0; nf < 4; nf++) {
                float v = acc[mf][nf][jj];
                s = fmaf(v, v, s);
                conv[(size_t)(m0 + rowl) * NQ + n0 + wc * 64 + nf * 16 + lr16] = v;
            }
            s += __shfl_xor(s, 1, 64);
            s += __shfl_xor(s, 2, 64);
            s += __shfl_xor(s, 4, 64);
            s += __shfl_xor(s, 8, 64);
            if (lr16 == 0) sred[wc][rowl] = s;
        }
    __syncthreads();
    if (t < 256) {
        float e = sred[0][t] + sred[1][t];   // rotation 2*nb   (cols n0..n0+127)
        float o = sred[2][t] + sred[3][t];   // rotation 2*nb+1 (cols n0+128..)
        float2* np = (float2*)&norms[(size_t)(pt0 + m0 + t) * 8 + nb * 2];
        *np = make_float2(e, o);
    }
}

__global__ void k_select(const float* __restrict__ conv, const float* __restrict__ norms,
                         float* __restrict__ out, int pt0, int rows) {
    int nwaves = gridDim.x * 4;
    int wav = (blockIdx.x * 256 + threadIdx.x) >> 6;
    int lane = threadIdx.x & 63;
    for (int task = wav; task < rows; task += nwaves) {
        int tu = __builtin_amdgcn_readfirstlane(task);
        int pt = pt0 + tu;
        if (pt >= PTS) continue;
        const float* np = norms + (size_t)pt * 8;
        float bs = np[0];
        int br = 0;
#pragma unroll
        for (int r = 1; r < 8; r++) {
            float v = np[r];
            if (v > bs) { bs = v; br = r; }  // strict >: first max = argmax
        }
        const float2 v = *(const float2*)&conv[(size_t)tu * NQ + br * 128 + lane * 2];
        float2 o;
        o.x = v.x * INVSS;
        o.y = v.y * INVSS;
        *(float2*)&out[(size_t)pt * O_ + lane * 2] = o;
    }
}

extern "C" void kernel_launch(void* const* d_in, const int* in_sizes, int n_in,
                              void* d_out, int out_size, void* d_ws, size_t ws_size,
                              hipStream_t stream) {
    const float* sig = (const float*)d_in[0];
    const float* bw = (const float*)d_in[1];
    const int* bi = (const int*)d_in[2];
    const float* kern = (const float*)d_in[3];
    float* out = (float*)d_out;
    char* ws = (char*)d_ws;

    const size_t sz_ksum = (size_t)T_ * R_ * O_ * NIN * sizeof(float);  // 1.31 MB
    const size_t sz_wt = (size_t)NQ * KLOG * sizeof(f16);               // 15.7 MB
    const size_t sz_norms = (size_t)PTSPAD * 8 * sizeof(float);         // 1.29 MB
    float* ksum = (float*)ws;
    f16* WT = (f16*)(ws + sz_ksum);
    float* norms = (float*)(ws + sz_ksum + sz_wt);
    char* dyn = ws + sz_ksum + sz_wt + sz_norms;

    size_t persist = sz_ksum + sz_wt + sz_norms;
    size_t avail = (ws_size > persist) ? (ws_size - persist) : 0;
    // per-row: X 10240 B + conv 4096 B
    long maxrows = (long)(avail / (size_t)(KPHY * 2 + NQ * 4));
    int chunk = (int)((maxrows / BM) * BM);
    if (chunk < BM) chunk = BM;
    if (chunk > PTSPAD) chunk = PTSPAD;

    f16* X = (f16*)dyn;
    float* conv = (float*)(dyn + (size_t)chunk * KPHY * sizeof(f16));

    k_ksum<<<(T_ * R_ * O_ * NIN + 255) / 256, 256, 0, stream>>>(kern, ksum);
    k_wt<<<(NQ * KSEG + 255) / 256, 256, 0, stream>>>(ksum, WT);

    for (int pt0 = 0; pt0 < PTS; pt0 += chunk) {
        int rem = PTS - pt0;
        int rows = (rem < chunk) ? rem : chunk;
        int rows_pad = (rows + BM - 1) & ~(BM - 1);
        k_interp<<<4096, 256, 0, stream>>>(sig, bw, bi, X, pt0, rows_pad);
        k_gemm<<<(rows_pad / BM) * 4, 512, 0, stream>>>(X, WT, conv, norms, pt0);
        k_select<<<2048, 256, 0, stream>>>(conv, norms, out, pt0, rows);
    }
}

// Round 9
// 1350.587 us; speedup vs baseline: 2.2780x; 1.0784x over previous
//
#include <hip/hip_runtime.h>
#include <hip/hip_bf16.h>

// ConvGeodesic: f16x3 split-precision MFMA GEMM (256x256xBK64), 4-phase
// pipelined K-loop with counted vmcnt (T3+T4) + setprio (T5), then select.
//   k_ksum:   Ksum = sum_k kernel
//   k_wt:     WT[q=(r,o)][k'=(seg,j,i,n)] f16 hi|hi|lo
//   k_interp: X[row][(j,i,n)] f16 hi|lo
//   k_gemm:   256x256 tile, BK=64, 8 waves (2x4). Per K-tile 4 phases
//     (kk, m-half): {ds_read | prefetch-issue | barrier | lgkm0 | 16 MFMA | vmcnt | barrier}.
//     Prefetch t+2 split 6@p3(t) + 2@p0(t+1); vmcnt(8) steady, 6 prologue,
//     2/0 epilogue. B-frags register-cached across m-half phases. XOR swizzle.
//   k_select: per point argmax over 8 norms -> copy winning 128 cols.

typedef _Float16 f16;
typedef _Float16 f16x8 __attribute__((ext_vector_type(8)));
typedef float f32x4 __attribute__((ext_vector_type(4)));

#define B_   2
#define M_   20000
#define T_   8
#define R_   5
#define NIN  64
#define O_   128
#define K_   4

#define PTS   (B_*M_)      // 40000
#define PTSPAD 40192       // 157*256
#define KSEG  2560         // T_*R_*NIN
#define KPHY  5120         // X cols: [hi | lo]
#define KLOG  7680         // GEMM K: hi*Whi + lo*Whi + hi*Wlo
#define NQ    1024         // T_*O_
#define SCALE 16.0f
#define INVSS (1.0f/(SCALE*SCALE))

#define BM    256
#define BK    64
#define TS    (KLOG/BK)    // 120 K-tiles

__global__ void k_ksum(const float* __restrict__ kern, float* __restrict__ ksum) {
    int i = blockIdx.x * 256 + threadIdx.x;
    const int total = T_ * R_ * O_ * NIN;
    if (i >= total) return;
    float s = 0.f;
#pragma unroll
    for (int k = 0; k < K_; k++) s += kern[k * total + i];
    ksum[i] = s;
}

__global__ void k_wt(const float* __restrict__ ksum, f16* __restrict__ wt) {
    int idx = blockIdx.x * 256 + threadIdx.x;  // over NQ*KSEG
    const int total = NQ * KSEG;
    if (idx >= total) return;
    int q = idx / KSEG;
    int k = idx - q * KSEG;
    int r = q >> 7, o = q & 127;
    int j = k / 320;
    int rem = k - j * 320;
    int i = rem >> 6, n = rem & 63;
    int t = (j + r) & 7;
    float v = SCALE * ksum[((((t * R_ + i) * O_ + o) << 6) + n)];
    f16 hi = (f16)v;
    f16 lo = (f16)(v - (float)hi);
    f16* row = wt + (size_t)q * KLOG;
    row[k] = hi;
    row[k + KSEG] = hi;
    row[k + 2 * KSEG] = lo;
}

// one wave per (local row, j); wave-uniform scalar weight loads.
__global__ void k_interp(const float* __restrict__ sig, const float* __restrict__ bw,
                         const int* __restrict__ bi, f16* __restrict__ X,
                         int pt0, int rows_pad) {
    int nwaves = gridDim.x * 4;
    int wav = (blockIdx.x * 256 + threadIdx.x) >> 6;
    int lane = threadIdx.x & 63;  // lane = n
    int ntask = rows_pad * T_;
    for (int task = wav; task < ntask; task += nwaves) {
        int tu = __builtin_amdgcn_readfirstlane(task);
        int lr = tu >> 3;         // T_ == 8
        int j = tu & 7;
        int pt = pt0 + lr;
        f16* rowp = X + (size_t)lr * KPHY + j * 320;
        if (pt >= PTS) {
#pragma unroll
            for (int i = 0; i < R_; i++) {
                rowp[i * 64 + lane] = (f16)0.f;
                rowp[KSEG + i * 64 + lane] = (f16)0.f;
            }
            continue;
        }
        int b = (pt >= M_) ? 1 : 0;
        const float* sb = sig + (size_t)b * M_ * NIN;
        const float* wp = bw + (size_t)pt * 120 + j * 15;
        const int* ip = bi + (size_t)pt * 120 + j * 15;
#pragma unroll
        for (int i = 0; i < R_; i++) {
            float w0 = wp[i * 3], w1 = wp[i * 3 + 1], w2 = wp[i * 3 + 2];
            int i0 = ip[i * 3], i1 = ip[i * 3 + 1], i2 = ip[i * 3 + 2];
            float x = w0 * sb[(size_t)i0 * NIN + lane];
            x = fmaf(w1, sb[(size_t)i1 * NIN + lane], x);
            x = fmaf(w2, sb[(size_t)i2 * NIN + lane], x);
            x *= SCALE;
            f16 hi = (f16)x;
            f16 lo = (f16)(x - (float)hi);
            rowp[i * 64 + lane] = hi;
            rowp[KSEG + i * 64 + lane] = lo;
        }
    }
}

#define SBAR()  __builtin_amdgcn_s_barrier()
#define SCHED() __builtin_amdgcn_sched_barrier(0)
#define LGKM0() asm volatile("s_waitcnt lgkmcnt(0)" ::: "memory")

__global__ __launch_bounds__(512, 1) void k_gemm(
    const f16* __restrict__ X, const f16* __restrict__ WT,
    float* __restrict__ conv, float* __restrict__ norms, int pt0) {
    // dbuf LDS: As/Bs [2][256][64] halfs = 64 KB each; sred 4 KB. 132 KB.
    __shared__ __align__(16) f16 As[2][256 * 64];
    __shared__ __align__(16) f16 Bs[2][256 * 64];
    __shared__ float sred[4][256];

    // bijective XCD-chunked swizzle (m204)
    int nwg = gridDim.x;
    int bq = nwg >> 3, br_ = nwg & 7;
    int xcd = blockIdx.x & 7, slot = blockIdx.x >> 3;
    int logical = (xcd < br_ ? xcd * (bq + 1) : br_ * (bq + 1) + (xcd - br_) * bq) + slot;
    int mblk = logical >> 2, nb = logical & 3;
    const int m0 = mblk * BM;
    const int n0 = nb * 256;

    const int t = threadIdx.x;
    const int w = t >> 6, lane = t & 63;
    const int wr = w >> 2, wc = w & 3;     // 2m x 4n waves; wave tile 128x64
    const int lq = lane >> 4, lr16 = lane & 15;
    const int fr = lr16 & 7;               // read-side swizzle bits
    const int src_off = (((t & 7) ^ ((t >> 3) & 7)) << 3);  // staging pre-swizzle

    f32x4 acc[8][4];
#pragma unroll
    for (int a = 0; a < 8; a++)
#pragma unroll
        for (int b = 0; b < 4; b++) acc[a][b] = (f32x4){0.f, 0.f, 0.f, 0.f};

    const f16* pA = X + (size_t)(m0 + (t >> 3)) * KPHY + src_off;
    const f16* pB = WT + (size_t)(n0 + (t >> 3)) * KLOG + src_off;

    // A/B quarter Q (rows Q*64..Q*64+63) of K-tile KT -> buffer BUF
#define GLA(Q, BUF, KT) do {                                                          \
        int k0_ = (KT) * BK;                                                          \
        int kA_ = k0_ - ((k0_ >= KPHY) ? KPHY : 0); /* seg2 re-reads x_hi */          \
        __builtin_amdgcn_global_load_lds(                                             \
            (const __attribute__((address_space(1))) void*)(pA + kA_ + (size_t)(Q) * 64 * KPHY), \
            (__attribute__((address_space(3))) void*)(&As[BUF][(Q) * 4096 + t * 8]), 16, 0, 0); \
    } while (0)
#define GLB(Q, BUF, KT) do {                                                          \
        int k0_ = (KT) * BK;                                                          \
        __builtin_amdgcn_global_load_lds(                                             \
            (const __attribute__((address_space(1))) void*)(pB + k0_ + (size_t)(Q) * 64 * KLOG), \
            (__attribute__((address_space(3))) void*)(&Bs[BUF][(Q) * 4096 + t * 8]), 16, 0, 0); \
    } while (0)

    // prologue: tile0 full (8), tile1 first-6 (A-Q0,Q2 + B-all)
    GLA(0, 0, 0); GLA(1, 0, 0); GLA(2, 0, 0); GLA(3, 0, 0);
    GLB(0, 0, 0); GLB(1, 0, 0); GLB(2, 0, 0); GLB(3, 0, 0);
    GLA(0, 1, 1); GLA(2, 1, 1);
    GLB(0, 1, 1); GLB(1, 1, 1); GLB(2, 1, 1); GLB(3, 1, 1);
    asm volatile("s_waitcnt vmcnt(6)" ::: "memory");  // ALL of tile0's 8 landed
    SBAR(); SCHED();

    f16x8 af[4], bf[4], bg[4];
    for (int kt = 0; kt < TS; ++kt) {
        const int b = kt & 1;
        const f16* Ac = &As[b][0];
        const f16* Bc = &Bs[b][0];
        const int cho0 = (lq ^ fr) << 3;          // kk=0 chunks
        const int cho1 = ((4 + lq) ^ fr) << 3;    // kk=1 chunks

        // ---- p0: (kk0, mh0) — reads A-Q(wr*2), B-all(kk0)
#pragma unroll
        for (int mf = 0; mf < 4; mf++)
            af[mf] = *(const f16x8*)(Ac + (wr * 128 + mf * 16 + lr16) * 64 + cho0);
#pragma unroll
        for (int nf = 0; nf < 4; nf++)
            bf[nf] = *(const f16x8*)(Bc + (wc * 64 + nf * 16 + lr16) * 64 + cho0);
        if (kt + 1 < TS) { GLA(1, b ^ 1, kt + 1); GLA(3, b ^ 1, kt + 1); }
        SBAR(); SCHED();
        LGKM0(); SCHED();
        __builtin_amdgcn_s_setprio(1);
#pragma unroll
        for (int mf = 0; mf < 4; mf++)
#pragma unroll
            for (int nf = 0; nf < 4; nf++)
                acc[mf][nf] = __builtin_amdgcn_mfma_f32_16x16x32_f16(af[mf], bf[nf], acc[mf][nf], 0, 0, 0);
        __builtin_amdgcn_s_setprio(0); SCHED();
        if (kt < TS - 1) asm volatile("s_waitcnt vmcnt(8)" ::: "memory");  // L(kt) landed
        else             asm volatile("s_waitcnt vmcnt(0)" ::: "memory");
        SBAR(); SCHED();

        // ---- p1: (kk0, mh1) — reads A-Q(wr*2+1); B reused
#pragma unroll
        for (int mf = 0; mf < 4; mf++)
            af[mf] = *(const f16x8*)(Ac + (wr * 128 + 64 + mf * 16 + lr16) * 64 + cho0);
        SBAR(); SCHED();
        LGKM0(); SCHED();
        __builtin_amdgcn_s_setprio(1);
#pragma unroll
        for (int mf = 0; mf < 4; mf++)
#pragma unroll
            for (int nf = 0; nf < 4; nf++)
                acc[4 + mf][nf] = __builtin_amdgcn_mfma_f32_16x16x32_f16(af[mf], bf[nf], acc[4 + mf][nf], 0, 0, 0);
        __builtin_amdgcn_s_setprio(0); SCHED();
        SBAR(); SCHED();

        // ---- p2: (kk1, mh0) — reads A-Q(wr*2) kk1, B-all(kk1)
#pragma unroll
        for (int mf = 0; mf < 4; mf++)
            af[mf] = *(const f16x8*)(Ac + (wr * 128 + mf * 16 + lr16) * 64 + cho1);
#pragma unroll
        for (int nf = 0; nf < 4; nf++)
            bg[nf] = *(const f16x8*)(Bc + (wc * 64 + nf * 16 + lr16) * 64 + cho1);
        SBAR(); SCHED();
        LGKM0(); SCHED();
        __builtin_amdgcn_s_setprio(1);
#pragma unroll
        for (int mf = 0; mf < 4; mf++)
#pragma unroll
            for (int nf = 0; nf < 4; nf++)
                acc[mf][nf] = __builtin_amdgcn_mfma_f32_16x16x32_f16(af[mf], bg[nf], acc[mf][nf], 0, 0, 0);
        __builtin_amdgcn_s_setprio(0); SCHED();
        SBAR(); SCHED();

        // ---- p3: (kk1, mh1) — reads A-Q(wr*2+1) kk1; issue tile kt+2 first-6
#pragma unroll
        for (int mf = 0; mf < 4; mf++)
            af[mf] = *(const f16x8*)(Ac + (wr * 128 + 64 + mf * 16 + lr16) * 64 + cho1);
        if (kt + 2 < TS) {
            GLA(0, b, kt + 2); GLA(2, b, kt + 2);
            GLB(0, b, kt + 2); GLB(1, b, kt + 2); GLB(2, b, kt + 2); GLB(3, b, kt + 2);
        }
        SBAR(); SCHED();
        LGKM0(); SCHED();
        __builtin_amdgcn_s_setprio(1);
#pragma unroll
        for (int mf = 0; mf < 4; mf++)
#pragma unroll
            for (int nf = 0; nf < 4; nf++)
                acc[4 + mf][nf] = __builtin_amdgcn_mfma_f32_16x16x32_f16(af[mf], bg[nf], acc[4 + mf][nf], 0, 0, 0);
        __builtin_amdgcn_s_setprio(0); SCHED();
        if (kt < TS - 2)       asm volatile("s_waitcnt vmcnt(8)" ::: "memory");  // F(kt+1) landed
        else if (kt == TS - 2) asm volatile("s_waitcnt vmcnt(2)" ::: "memory");
        SBAR(); SCHED();
    }
#undef GLA
#undef GLB

    // epilogue: relu -> conv store (post-relu) + per-row norms for 2 rotations
#pragma unroll
    for (int mf = 0; mf < 8; mf++)
#pragma unroll
        for (int nf = 0; nf < 4; nf++)
#pragma unroll
            for (int jj = 0; jj < 4; jj++)
                acc[mf][nf][jj] = fmaxf(acc[mf][nf][jj], 0.f);

#pragma unroll
    for (int mf = 0; mf < 8; mf++)
#pragma unroll
        for (int jj = 0; jj < 4; jj++) {
            int rowl = wr * 128 + mf * 16 + lq * 4 + jj;
            float s = 0.f;
#pragma unroll
            for (int nf = 0; nf < 4; nf++) {
                float v = acc[mf][nf][jj];
                s = fmaf(v, v, s);
                conv[(size_t)(m0 + rowl) * NQ + n0 + wc * 64 + nf * 16 + lr16] = v;
            }
            s += __shfl_xor(s, 1, 64);
            s += __shfl_xor(s, 2, 64);
            s += __shfl_xor(s, 4, 64);
            s += __shfl_xor(s, 8, 64);
            if (lr16 == 0) sred[wc][rowl] = s;
        }
    __syncthreads();
    if (t < 256) {
        float e = sred[0][t] + sred[1][t];   // rotation 2*nb
        float o = sred[2][t] + sred[3][t];   // rotation 2*nb+1
        float2* np = (float2*)&norms[(size_t)(pt0 + m0 + t) * 8 + nb * 2];
        *np = make_float2(e, o);
    }
}

__global__ void k_select(const float* __restrict__ conv, const float* __restrict__ norms,
                         float* __restrict__ out, int pt0, int rows) {
    int nwaves = gridDim.x * 4;
    int wav = (blockIdx.x * 256 + threadIdx.x) >> 6;
    int lane = threadIdx.x & 63;
    for (int task = wav; task < rows; task += nwaves) {
        int tu = __builtin_amdgcn_readfirstlane(task);
        int pt = pt0 + tu;
        if (pt >= PTS) continue;
        const float* np = norms + (size_t)pt * 8;
        float bs = np[0];
        int br = 0;
#pragma unroll
        for (int r = 1; r < 8; r++) {
            float v = np[r];
            if (v > bs) { bs = v; br = r; }  // strict >: first max = argmax
        }
        const float2 v = *(const float2*)&conv[(size_t)tu * NQ + br * 128 + lane * 2];
        float2 o;
        o.x = v.x * INVSS;
        o.y = v.y * INVSS;
        *(float2*)&out[(size_t)pt * O_ + lane * 2] = o;
    }
}

extern "C" void kernel_launch(void* const* d_in, const int* in_sizes, int n_in,
                              void* d_out, int out_size, void* d_ws, size_t ws_size,
                              hipStream_t stream) {
    const float* sig = (const float*)d_in[0];
    const float* bw = (const float*)d_in[1];
    const int* bi = (const int*)d_in[2];
    const float* kern = (const float*)d_in[3];
    float* out = (float*)d_out;
    char* ws = (char*)d_ws;

    const size_t sz_ksum = (size_t)T_ * R_ * O_ * NIN * sizeof(float);  // 1.31 MB
    const size_t sz_wt = (size_t)NQ * KLOG * sizeof(f16);               // 15.7 MB
    const size_t sz_norms = (size_t)PTSPAD * 8 * sizeof(float);         // 1.29 MB
    float* ksum = (float*)ws;
    f16* WT = (f16*)(ws + sz_ksum);
    float* norms = (float*)(ws + sz_ksum + sz_wt);
    char* dyn = ws + sz_ksum + sz_wt + sz_norms;

    size_t persist = sz_ksum + sz_wt + sz_norms;
    size_t avail = (ws_size > persist) ? (ws_size - persist) : 0;
    // per-row: X 10240 B + conv 4096 B
    long maxrows = (long)(avail / (size_t)(KPHY * 2 + NQ * 4));
    int chunk = (int)((maxrows / BM) * BM);
    if (chunk < BM) chunk = BM;
    if (chunk > PTSPAD) chunk = PTSPAD;

    f16* X = (f16*)dyn;
    float* conv = (float*)(dyn + (size_t)chunk * KPHY * sizeof(f16));

    k_ksum<<<(T_ * R_ * O_ * NIN + 255) / 256, 256, 0, stream>>>(kern, ksum);
    k_wt<<<(NQ * KSEG + 255) / 256, 256, 0, stream>>>(ksum, WT);

    for (int pt0 = 0; pt0 < PTS; pt0 += chunk) {
        int rem = PTS - pt0;
        int rows = (rem < chunk) ? rem : chunk;
        int rows_pad = (rows + BM - 1) & ~(BM - 1);
        k_interp<<<8192, 256, 0, stream>>>(sig, bw, bi, X, pt0, rows_pad);
        k_gemm<<<(rows_pad / BM) * 4, 512, 0, stream>>>(X, WT, conv, norms, pt0);
        k_select<<<2048, 256, 0, stream>>>(conv, norms, out, pt0, rows);
    }
}